// Round 1
// baseline (346.122 us; speedup 1.0000x reference)
//
#include <hip/hip_runtime.h>

typedef _Float16 f16;
typedef _Float16 f16x2 __attribute__((ext_vector_type(2)));
typedef _Float16 f16x4 __attribute__((ext_vector_type(4)));
typedef _Float16 f16x8 __attribute__((ext_vector_type(8)));
typedef float f32x4v __attribute__((ext_vector_type(4)));

#define AS1 __attribute__((address_space(1)))
#define AS3 __attribute__((address_space(3)))

// async global->LDS, 16B per lane; LDS dest = wave-uniform base + lane*16
__device__ __forceinline__ void gload_lds16(const f16* g, f16* l) {
  __builtin_amdgcn_global_load_lds((const AS1 unsigned int*)g,
                                   (AS3 unsigned int*)l, 16, 0, 0);
}

// ---------------------------------------------------------------------------
// prep: fp32 -> fp16 straight conversions (Qb, Kb, Vb, Wq, Wk, Wv), float4 io
// group = 4 elements. Region boundaries in groups:
//   Qb [0,1048576) Kb [..,5242880) Vb [..,9437184)
//   Wq [..,9699328) Wk [..,9961472) Wv [..,10223616)
// ---------------------------------------------------------------------------
__global__ __launch_bounds__(256) void prep_kernel(
    const float* __restrict__ Q_seq, const float* __restrict__ K_seq,
    const float* __restrict__ V_seq,
    const float* __restrict__ Wq, const float* __restrict__ Wk,
    const float* __restrict__ Wv,
    f16* __restrict__ Qb, f16* __restrict__ Kb, f16* __restrict__ Vb,
    f16* __restrict__ Wqb, f16* __restrict__ Wkb, f16* __restrict__ Wvb)
{
  const long long g = (long long)blockIdx.x * 256 + threadIdx.x;
  const float* s;
  f16* d;
  if (g < 1048576) {
    s = Q_seq + g * 4; d = Qb + g * 4;
  } else if (g < 5242880) {
    long long e = (g - 1048576) * 4; s = K_seq + e; d = Kb + e;
  } else if (g < 9437184) {
    long long e = (g - 5242880) * 4; s = V_seq + e; d = Vb + e;
  } else if (g < 9699328) {
    long long e = (g - 9437184) * 4; s = Wq + e; d = Wqb + e;
  } else if (g < 9961472) {
    long long e = (g - 9699328) * 4; s = Wk + e; d = Wkb + e;
  } else {
    long long e = (g - 9961472) * 4; s = Wv + e; d = Wvb + e;
  }
  float4 v = *(const float4*)s;
  f16x4 o;
  o.x = (f16)v.x; o.y = (f16)v.y; o.z = (f16)v.z; o.w = (f16)v.w;
  *(f16x4*)d = o;
}

// ---------------------------------------------------------------------------
// 128x128 tile GEMM, BK=32, C = A(MxK) * W(NxK)^T + bias.  K = N = 1024.
// 4 waves, each 64x64 out (4x4 MFMA frags of 16x16x32 f16).
// Epilogue row remap: orow = (arow>>rowShift)*outStride + (arow&mask) + rowOff
// (packs per-batch sub-blocks into the [B,160,1024] concat layout).
// ---------------------------------------------------------------------------
__device__ __forceinline__ void gemm_tile_128(
    const f16* __restrict__ A, const f16* __restrict__ W,
    const float* __restrict__ bias, f16* __restrict__ C,
    int m0, int n0, int rowShift, int outStride, int rowOff,
    f16* As, f16* Bs)
{
  const int t = threadIdx.x;
  const int w = t >> 6, lane = t & 63;
  const int wr = w >> 1, wc = w & 1;
  const int sr = lane >> 2, sc = (lane & 3) * 8;

  const f16* gA0 = A + (long long)(m0 + (w * 2 + 0) * 16 + sr) * 1024 + sc;
  const f16* gA1 = A + (long long)(m0 + (w * 2 + 1) * 16 + sr) * 1024 + sc;
  const f16* gB0 = W + (long long)(n0 + (w * 2 + 0) * 16 + sr) * 1024 + sc;
  const f16* gB1 = W + (long long)(n0 + (w * 2 + 1) * 16 + sr) * 1024 + sc;
  f16* lA0 = As + (w * 2 + 0) * 512;
  f16* lA1 = As + (w * 2 + 1) * 512;
  f16* lB0 = Bs + (w * 2 + 0) * 512;
  f16* lB1 = Bs + (w * 2 + 1) * 512;

  f32x4v acc[4][4];
#pragma unroll
  for (int i = 0; i < 4; ++i)
#pragma unroll
    for (int j = 0; j < 4; ++j) acc[i][j] = (f32x4v){0.f, 0.f, 0.f, 0.f};

  const int fr = lane & 15;          // fragment row (A) / col (B)
  const int fk = (lane >> 4) * 8;    // k-chunk
  const f16* pA = As + (wr * 64 + fr) * 32 + fk;
  const f16* pB = Bs + (wc * 64 + fr) * 32 + fk;

  for (int k0 = 0; k0 < 1024; k0 += 32) {
    gload_lds16(gA0 + k0, lA0);
    gload_lds16(gA1 + k0, lA1);
    gload_lds16(gB0 + k0, lB0);
    gload_lds16(gB1 + k0, lB1);
    __syncthreads();   // drains vmcnt before barrier -> LDS tiles ready
    f16x8 av[4], bv[4];
#pragma unroll
    for (int i = 0; i < 4; ++i) av[i] = *(const f16x8*)(pA + i * 16 * 32);
#pragma unroll
    for (int i = 0; i < 4; ++i) bv[i] = *(const f16x8*)(pB + i * 16 * 32);
#pragma unroll
    for (int i = 0; i < 4; ++i)
#pragma unroll
      for (int j = 0; j < 4; ++j)
        acc[i][j] = __builtin_amdgcn_mfma_f32_16x16x32_f16(av[i], bv[j],
                                                           acc[i][j], 0, 0, 0);
    __syncthreads();   // all reads done before next stage overwrites
  }

  const int rowMask = (1 << rowShift) - 1;
  float bn[4];
#pragma unroll
  for (int j = 0; j < 4; ++j) bn[j] = bias[n0 + wc * 64 + j * 16 + fr];
#pragma unroll
  for (int i = 0; i < 4; ++i) {
#pragma unroll
    for (int j = 0; j < 4; ++j) {
#pragma unroll
      for (int v = 0; v < 4; ++v) {
        // verified C/D layout: col = lane&15, row = (lane>>4)*4 + v
        int arow = m0 + wr * 64 + i * 16 + (lane >> 4) * 4 + v;
        int orow = (arow >> rowShift) * outStride + (arow & rowMask) + rowOff;
        int col = n0 + wc * 64 + j * 16 + fr;
        C[(long long)orow * 1024 + col] = (f16)(acc[i][j][v] + bn[j]);
      }
    }
  }
}

// big GEMMs: A = Kb or Vb (M=16384, per-batch 128 rows -> stride-160 rows)
__global__ __launch_bounds__(256) void gemm_kv(
    const f16* __restrict__ A, const f16* __restrict__ W,
    const float* __restrict__ bias, f16* __restrict__ C)
{
  __shared__ __align__(16) f16 As[128 * 32];
  __shared__ __align__(16) f16 Bs[128 * 32];
  gemm_tile_128(A, W, bias, C, blockIdx.y * 128, blockIdx.x * 128,
                7, 160, 0, As, Bs);
}

// Q-side projections (M=4096): z=0 -> Qh, z=1 -> Kh title rows, z=2 -> Vh title
__global__ __launch_bounds__(256) void gemm_q3(
    const f16* __restrict__ Qb,
    const f16* __restrict__ Wqb, const f16* __restrict__ Wkb,
    const f16* __restrict__ Wvb,
    const float* __restrict__ bq, const float* __restrict__ bk,
    const float* __restrict__ bv,
    f16* __restrict__ Qh, f16* __restrict__ Kh, f16* __restrict__ Vh)
{
  __shared__ __align__(16) f16 As[128 * 32];
  __shared__ __align__(16) f16 Bs[128 * 32];
  const int z = blockIdx.z;
  const f16* W = (z == 0) ? Wqb : (z == 1) ? Wkb : Wvb;
  const float* bias = (z == 0) ? bq : (z == 1) ? bk : bv;
  f16* C = (z == 0) ? Qh : (z == 1) ? Kh : Vh;
  const int outStride = (z == 0) ? 32 : 160;
  const int rowOff = (z == 0) ? 0 : 128;
  gemm_tile_128(Qb, W, bias, C, blockIdx.y * 128, blockIdx.x * 128,
                5, outStride, rowOff, As, Bs);
}

// ---------------------------------------------------------------------------
// attention: one block per (b,h); 4 waves x 8 q-rows each.
// scores via v_dot2_f32_f16 (fp32 accum), exp-based masked normalization,
// PV via __shfl broadcast of unnormalized weights, 8 q batched per V pass.
// ---------------------------------------------------------------------------
__global__ __launch_bounds__(256) void attn_kernel(
    const f16* __restrict__ Qh, const f16* __restrict__ Kh,
    const f16* __restrict__ Vh,
    const float* __restrict__ title, const float* __restrict__ body,
    float* __restrict__ out)
{
  __shared__ __align__(16) f16 Qs[32 * 64];
  __shared__ __align__(16) f16 Ks[160 * 68];  // pad 68: conflict-free f16x2 reads
  __shared__ __align__(16) f16 Vs[160 * 64];
  __shared__ float tks[32];

  const int bh = blockIdx.x, b = bh >> 4, h = bh & 15;
  const int t = threadIdx.x, w = t >> 6, lane = t & 63;

  for (int i = t; i < 2048; i += 256) {
    int q = i >> 6, d = i & 63;
    Qs[i] = Qh[((long long)(b * 32 + q) << 10) + h * 64 + d];
  }
  for (int i = t; i < 10240; i += 256) {
    int k = i >> 6, d = i & 63;
    long long src = ((long long)(b * 160 + k) << 10) + h * 64 + d;
    Ks[k * 68 + d] = Kh[src];
    Vs[i] = Vh[src];
  }
  if (t < 32) tks[t] = title[b * 32 + t];
  __syncthreads();

  const int k0i = lane;
  const int k1i = 64 + lane;
  const int k2i = 128 + (lane & 31);  // lanes>=32 duplicate, masked to 0

  float e0[8], e1[8], e2[8], inv[8];
#pragma unroll
  for (int qq = 0; qq < 8; ++qq) {
    const int q = qq * 4 + w;
    const float tq = title[b * 32 + q];
    f16x2 qr[32];
#pragma unroll
    for (int j = 0; j < 32; ++j) qr[j] = *(const f16x2*)(Qs + q * 64 + j * 2);
    float s0 = 0.f, s1 = 0.f, s2 = 0.f;
#pragma unroll
    for (int j = 0; j < 32; ++j) {
      s0 = __builtin_amdgcn_fdot2(qr[j], *(const f16x2*)(Ks + k0i * 68 + j * 2), s0, false);
      s1 = __builtin_amdgcn_fdot2(qr[j], *(const f16x2*)(Ks + k1i * 68 + j * 2), s1, false);
      s2 = __builtin_amdgcn_fdot2(qr[j], *(const f16x2*)(Ks + k2i * 68 + j * 2), s2, false);
    }
    const float m0 = body[(long long)(b * 32 + q) * 128 + k0i] * tq;
    const float m1 = body[(long long)(b * 32 + q) * 128 + k1i] * tq;
    const float m2 = (lane < 32) ? tks[lane & 31] * tq : 0.f;
    e0[qq] = __expf(s0 * 0.125f) * m0;
    e1[qq] = __expf(s1 * 0.125f) * m1;
    e2[qq] = __expf(s2 * 0.125f) * m2;
    float esum = e0[qq] + e1[qq] + e2[qq];
#pragma unroll
    for (int off = 32; off > 0; off >>= 1) esum += __shfl_xor(esum, off);
    inv[qq] = 1.f / (esum + 1e-8f);
  }

  float acc[8] = {0.f, 0.f, 0.f, 0.f, 0.f, 0.f, 0.f, 0.f};
#pragma unroll 2
  for (int kk = 0; kk < 64; ++kk) {
    float v = (float)Vs[kk * 64 + lane];
#pragma unroll
    for (int qq = 0; qq < 8; ++qq) acc[qq] += __shfl(e0[qq], kk) * v;
  }
#pragma unroll 2
  for (int kk = 0; kk < 64; ++kk) {
    float v = (float)Vs[(64 + kk) * 64 + lane];
#pragma unroll
    for (int qq = 0; qq < 8; ++qq) acc[qq] += __shfl(e1[qq], kk) * v;
  }
#pragma unroll 2
  for (int kk = 0; kk < 32; ++kk) {
    float v = (float)Vs[(128 + kk) * 64 + lane];
#pragma unroll
    for (int qq = 0; qq < 8; ++qq) acc[qq] += __shfl(e2[qq], kk) * v;
  }

#pragma unroll
  for (int qq = 0; qq < 8; ++qq) {
    const int q = qq * 4 + w;
    out[((long long)(b * 32 + q) << 10) + h * 64 + lane] = acc[qq] * inv[qq];
  }
}

// ---------------------------------------------------------------------------
extern "C" void kernel_launch(void* const* d_in, const int* in_sizes, int n_in,
                              void* d_out, int out_size, void* d_ws, size_t ws_size,
                              hipStream_t stream) {
  const float* Q_seq = (const float*)d_in[0];
  const float* K_seq = (const float*)d_in[1];
  const float* V_seq = (const float*)d_in[2];
  const float* title = (const float*)d_in[3];
  const float* body  = (const float*)d_in[4];
  const float* Wq = (const float*)d_in[5];
  const float* bq = (const float*)d_in[6];
  const float* Wk = (const float*)d_in[7];
  const float* bk = (const float*)d_in[8];
  const float* Wv = (const float*)d_in[9];
  const float* bv = (const float*)d_in[10];
  float* out = (float*)d_out;

  f16* ws = (f16*)d_ws;
  f16* Qb  = ws;                  // 4,194,304
  f16* Kb  = Qb + 4194304;        // 16,777,216
  f16* Vb  = Kb + 16777216;       // 16,777,216
  f16* Wqb = Vb + 16777216;       // 1,048,576
  f16* Wkb = Wqb + 1048576;
  f16* Wvb = Wkb + 1048576;
  f16* Qh  = Wvb + 1048576;       // [B*32][1024]
  f16* Kh  = Qh + 4194304;        // [B*160][1024]
  f16* Vh  = Kh + 20971520;       // [B*160][1024]  (total ~166 MB)

  prep_kernel<<<39936, 256, 0, stream>>>(Q_seq, K_seq, V_seq, Wq, Wk, Wv,
                                         Qb, Kb, Vb, Wqb, Wkb, Wvb);
  // grid x = n-tile (8) fastest -> consecutive blocks share the A panel (L2)
  gemm_kv<<<dim3(8, 128), 256, 0, stream>>>(Kb, Wkb, bk, Kh);
  gemm_kv<<<dim3(8, 128), 256, 0, stream>>>(Vb, Wvb, bv, Vh);
  gemm_q3<<<dim3(8, 32, 3), 256, 0, stream>>>(Qb, Wqb, Wkb, Wvb, bq, bk, bv,
                                              Qh, Kh, Vh);
  attn_kernel<<<2048, 256, 0, stream>>>(Qh, Kh, Vh, title, body, out);
}

// Round 3
// 216.462 us; speedup vs baseline: 1.5990x; 1.5990x over previous
//
#include <hip/hip_runtime.h>

typedef _Float16 f16;
typedef _Float16 f16x2 __attribute__((ext_vector_type(2)));
typedef _Float16 f16x4 __attribute__((ext_vector_type(4)));
typedef _Float16 f16x8 __attribute__((ext_vector_type(8)));
typedef float f32x4v __attribute__((ext_vector_type(4)));

#define AS1 __attribute__((address_space(1)))
#define AS3 __attribute__((address_space(3)))

// async global->LDS, 16B per lane; LDS dest = wave-uniform base + lane*16
__device__ __forceinline__ void gload_lds16(const f16* g, f16* l) {
  __builtin_amdgcn_global_load_lds((const AS1 unsigned int*)g,
                                   (AS3 unsigned int*)l, 16, 0, 0);
}

// ---------------------------------------------------------------------------
// prep: fp32 -> fp16 straight conversions (Qb, Kb, Vb, Wq, Wk, Wv), float4 io
// ---------------------------------------------------------------------------
__global__ __launch_bounds__(256) void prep_kernel(
    const float* __restrict__ Q_seq, const float* __restrict__ K_seq,
    const float* __restrict__ V_seq,
    const float* __restrict__ Wq, const float* __restrict__ Wk,
    const float* __restrict__ Wv,
    f16* __restrict__ Qb, f16* __restrict__ Kb, f16* __restrict__ Vb,
    f16* __restrict__ Wqb, f16* __restrict__ Wkb, f16* __restrict__ Wvb)
{
  const long long g = (long long)blockIdx.x * 256 + threadIdx.x;
  const float* s;
  f16* d;
  if (g < 1048576) {
    s = Q_seq + g * 4; d = Qb + g * 4;
  } else if (g < 5242880) {
    long long e = (g - 1048576) * 4; s = K_seq + e; d = Kb + e;
  } else if (g < 9437184) {
    long long e = (g - 5242880) * 4; s = V_seq + e; d = Vb + e;
  } else if (g < 9699328) {
    long long e = (g - 9437184) * 4; s = Wq + e; d = Wqb + e;
  } else if (g < 9961472) {
    long long e = (g - 9699328) * 4; s = Wk + e; d = Wkb + e;
  } else {
    long long e = (g - 9961472) * 4; s = Wv + e; d = Wvb + e;
  }
  float4 v = *(const float4*)s;
  f16x4 o;
  o.x = (f16)v.x; o.y = (f16)v.y; o.z = (f16)v.z; o.w = (f16)v.w;
  *(f16x4*)d = o;
}

// ---------------------------------------------------------------------------
// 128x128 tile GEMM, BK=32, C = A(MxK) * W(NxK)^T + bias.  K = N = 1024.
// ---------------------------------------------------------------------------
__device__ __forceinline__ void gemm_tile_128(
    const f16* __restrict__ A, const f16* __restrict__ W,
    const float* __restrict__ bias, f16* __restrict__ C,
    int m0, int n0, int rowShift, int outStride, int rowOff,
    f16* As, f16* Bs)
{
  const int t = threadIdx.x;
  const int w = t >> 6, lane = t & 63;
  const int wr = w >> 1, wc = w & 1;
  const int sr = lane >> 2, sc = (lane & 3) * 8;

  const f16* gA0 = A + (long long)(m0 + (w * 2 + 0) * 16 + sr) * 1024 + sc;
  const f16* gA1 = A + (long long)(m0 + (w * 2 + 1) * 16 + sr) * 1024 + sc;
  const f16* gB0 = W + (long long)(n0 + (w * 2 + 0) * 16 + sr) * 1024 + sc;
  const f16* gB1 = W + (long long)(n0 + (w * 2 + 1) * 16 + sr) * 1024 + sc;
  f16* lA0 = As + (w * 2 + 0) * 512;
  f16* lA1 = As + (w * 2 + 1) * 512;
  f16* lB0 = Bs + (w * 2 + 0) * 512;
  f16* lB1 = Bs + (w * 2 + 1) * 512;

  f32x4v acc[4][4];
#pragma unroll
  for (int i = 0; i < 4; ++i)
#pragma unroll
    for (int j = 0; j < 4; ++j) acc[i][j] = (f32x4v){0.f, 0.f, 0.f, 0.f};

  const int fr = lane & 15;
  const int fk = (lane >> 4) * 8;
  const f16* pA = As + (wr * 64 + fr) * 32 + fk;
  const f16* pB = Bs + (wc * 64 + fr) * 32 + fk;

  for (int k0 = 0; k0 < 1024; k0 += 32) {
    gload_lds16(gA0 + k0, lA0);
    gload_lds16(gA1 + k0, lA1);
    gload_lds16(gB0 + k0, lB0);
    gload_lds16(gB1 + k0, lB1);
    __syncthreads();
    f16x8 av[4], bv[4];
#pragma unroll
    for (int i = 0; i < 4; ++i) av[i] = *(const f16x8*)(pA + i * 16 * 32);
#pragma unroll
    for (int i = 0; i < 4; ++i) bv[i] = *(const f16x8*)(pB + i * 16 * 32);
#pragma unroll
    for (int i = 0; i < 4; ++i)
#pragma unroll
      for (int j = 0; j < 4; ++j)
        acc[i][j] = __builtin_amdgcn_mfma_f32_16x16x32_f16(av[i], bv[j],
                                                           acc[i][j], 0, 0, 0);
    __syncthreads();
  }

  const int rowMask = (1 << rowShift) - 1;
  float bn[4];
#pragma unroll
  for (int j = 0; j < 4; ++j) bn[j] = bias[n0 + wc * 64 + j * 16 + fr];
#pragma unroll
  for (int i = 0; i < 4; ++i) {
#pragma unroll
    for (int j = 0; j < 4; ++j) {
#pragma unroll
      for (int v = 0; v < 4; ++v) {
        int arow = m0 + wr * 64 + i * 16 + (lane >> 4) * 4 + v;
        int orow = (arow >> rowShift) * outStride + (arow & rowMask) + rowOff;
        int col = n0 + wc * 64 + j * 16 + fr;
        C[(long long)orow * 1024 + col] = (f16)(acc[i][j][v] + bn[j]);
      }
    }
  }
}

__global__ __launch_bounds__(256) void gemm_kv(
    const f16* __restrict__ A, const f16* __restrict__ W,
    const float* __restrict__ bias, f16* __restrict__ C)
{
  __shared__ __align__(16) f16 As[128 * 32];
  __shared__ __align__(16) f16 Bs[128 * 32];
  gemm_tile_128(A, W, bias, C, blockIdx.y * 128, blockIdx.x * 128,
                7, 160, 0, As, Bs);
}

__global__ __launch_bounds__(256) void gemm_q3(
    const f16* __restrict__ Qb,
    const f16* __restrict__ Wqb, const f16* __restrict__ Wkb,
    const f16* __restrict__ Wvb,
    const float* __restrict__ bq, const float* __restrict__ bk,
    const float* __restrict__ bv,
    f16* __restrict__ Qh, f16* __restrict__ Kh, f16* __restrict__ Vh)
{
  __shared__ __align__(16) f16 As[128 * 32];
  __shared__ __align__(16) f16 Bs[128 * 32];
  const int z = blockIdx.z;
  const f16* W = (z == 0) ? Wqb : (z == 1) ? Wkb : Wvb;
  const float* bias = (z == 0) ? bq : (z == 1) ? bk : bv;
  f16* C = (z == 0) ? Qh : (z == 1) ? Kh : Vh;
  const int outStride = (z == 0) ? 32 : 160;
  const int rowOff = (z == 0) ? 0 : 128;
  gemm_tile_128(Qb, W, bias, C, blockIdx.y * 128, blockIdx.x * 128,
                5, outStride, rowOff, As, Bs);
}

// ---------------------------------------------------------------------------
// MFMA attention: one block per (b,h), 4 waves.
// Phase A: S^T = mfma(A=K, B=Q) per key-tile -> C[row=key][col=q]
//          (q = lane&15 -> matches PV A-operand layout after LDS roundtrip)
// Phase B: P (=exp(S/8)*mask, fp16) written into dead K buffer.
// Phase C: O = mfma(A=P, B=V) ; each wave owns a 16-wide d slice, all keys.
// Normalization: inv[q] = title[q] / (rowsum + 1e-8) applied at the store.
// ---------------------------------------------------------------------------
__global__ __launch_bounds__(256) void attn_kernel(
    const f16* __restrict__ Qh, const f16* __restrict__ Kh,
    const f16* __restrict__ Vh,
    const float* __restrict__ title, const float* __restrict__ body,
    float* __restrict__ out)
{
  __shared__ __align__(16) f16 Qs[32 * 72];    // stride 144B (b128-friendly)
  __shared__ __align__(16) f16 Ks[160 * 72];   // reused as Ps[32][168] (336B)
  __shared__ __align__(16) f16 Vs[160 * 68];   // stride 136B (2-way max on u16)
  __shared__ float rs[4][32];
  __shared__ float invs[32];

  const int bh = blockIdx.x, b = bh >> 4, h = bh & 15;
  const int t = threadIdx.x, w = t >> 6, lane = t & 63;
  const int c = lane & 15, g = lane >> 4;

  const long long qbase = ((long long)(b * 32) << 10) + h * 64;
  const long long kbase = ((long long)(b * 160) << 10) + h * 64;

  // ---- stage Q (32 rows x 8 chunks), K,V (160 rows x 8 chunks) ----
  {
    int row = t >> 3, ch = t & 7;
    *(f16x8*)(Qs + row * 72 + ch * 8) =
        *(const f16x8*)(Qh + qbase + (long long)row * 1024 + ch * 8);
  }
#pragma unroll
  for (int r = 0; r < 5; ++r) {
    int i = t + r * 256;
    int row = i >> 3, ch = i & 7;
    *(f16x8*)(Ks + row * 72 + ch * 8) =
        *(const f16x8*)(Kh + kbase + (long long)row * 1024 + ch * 8);
    f16x8 vv = *(const f16x8*)(Vh + kbase + (long long)row * 1024 + ch * 8);
    f16x4 vlo = __builtin_shufflevector(vv, vv, 0, 1, 2, 3);
    f16x4 vhi = __builtin_shufflevector(vv, vv, 4, 5, 6, 7);
    *(f16x4*)(Vs + row * 68 + ch * 8) = vlo;
    *(f16x4*)(Vs + row * 68 + ch * 8 + 4) = vhi;
  }
  __syncthreads();

  // ---- Q fragments (reused across key tiles): Q[q=qt*16+c][d=32s+8g+j] ----
  f16x8 qf[2][2];
#pragma unroll
  for (int qt = 0; qt < 2; ++qt)
#pragma unroll
    for (int s = 0; s < 2; ++s)
      qf[qt][s] = *(const f16x8*)(Qs + (qt * 16 + c) * 72 + s * 32 + g * 8);

  // key-tile split over waves: {3,3,2,2}
  const int cnt = (w < 2) ? 3 : 2;
  const int tile0 = (w < 2) ? w * 3 : 6 + (w - 2) * 2;

  f16x4 pp[3][2];
  float rsum[2] = {0.f, 0.f};

#pragma unroll
  for (int i = 0; i < 3; ++i) {
    if (i < cnt) {
      const int kt = tile0 + i;
      // K fragments: K[key=kt*16+c][d=32s+8g+j]
      f16x8 kf0 = *(const f16x8*)(Ks + (kt * 16 + c) * 72 + 0 + g * 8);
      f16x8 kf1 = *(const f16x8*)(Ks + (kt * 16 + c) * 72 + 32 + g * 8);
#pragma unroll
      for (int qt = 0; qt < 2; ++qt) {
        f32x4v s4 = (f32x4v){0.f, 0.f, 0.f, 0.f};
        s4 = __builtin_amdgcn_mfma_f32_16x16x32_f16(kf0, qf[qt][0], s4, 0, 0, 0);
        s4 = __builtin_amdgcn_mfma_f32_16x16x32_f16(kf1, qf[qt][1], s4, 0, 0, 0);
        // mask: q = qt*16+c, keys = kt*16+4g+v
        float4 m4;
        if (kt < 8) {
          m4 = *(const float4*)(body +
                ((long long)(b * 32 + qt * 16 + c)) * 128 + kt * 16 + 4 * g);
        } else {
          m4 = *(const float4*)(title + b * 32 + (kt - 8) * 16 + 4 * g);
        }
        float e0 = __expf(s4[0] * 0.125f) * m4.x;
        float e1 = __expf(s4[1] * 0.125f) * m4.y;
        float e2 = __expf(s4[2] * 0.125f) * m4.z;
        float e3 = __expf(s4[3] * 0.125f) * m4.w;
        rsum[qt] += (e0 + e1) + (e2 + e3);
        f16x4 p4;
        p4.x = (f16)e0; p4.y = (f16)e1; p4.z = (f16)e2; p4.w = (f16)e3;
        pp[i][qt] = p4;
      }
    }
  }

  // row-sum partials: sum over g groups (lanes c, c+16, c+32, c+48)
#pragma unroll
  for (int qt = 0; qt < 2; ++qt) {
    rsum[qt] += __shfl_xor(rsum[qt], 16);
    rsum[qt] += __shfl_xor(rsum[qt], 32);
  }
  if (lane < 16) {
    rs[w][c] = rsum[0];
    rs[w][16 + c] = rsum[1];
  }
  __syncthreads();  // all K reads + rs writes complete

  // ---- write P into dead K buffer: P[q][key], stride 168 f16 ----
  f16* Ps = Ks;
#pragma unroll
  for (int i = 0; i < 3; ++i) {
    if (i < cnt) {
      const int kt = tile0 + i;
#pragma unroll
      for (int qt = 0; qt < 2; ++qt)
        *(f16x4*)(Ps + (qt * 16 + c) * 168 + kt * 16 + 4 * g) = pp[i][qt];
    }
  }
  if (t < 32) {
    float ssum = rs[0][t] + rs[1][t] + rs[2][t] + rs[3][t];
    invs[t] = title[b * 32 + t] / (ssum + 1e-8f);
  }
  __syncthreads();  // P + invs ready

  // ---- PV: O[q][d] ; wave owns d-slice 16w..16w+15, all 160 keys ----
  f32x4v o[2] = {(f32x4v){0.f, 0.f, 0.f, 0.f}, (f32x4v){0.f, 0.f, 0.f, 0.f}};
#pragma unroll
  for (int s = 0; s < 5; ++s) {
    f16x8 vf;
#pragma unroll
    for (int j = 0; j < 8; ++j)
      vf[j] = Vs[(32 * s + 8 * g + j) * 68 + 16 * w + c];
#pragma unroll
    for (int qt = 0; qt < 2; ++qt) {
      f16x8 pf = *(const f16x8*)(Ps + (qt * 16 + c) * 168 + s * 32 + g * 8);
      o[qt] = __builtin_amdgcn_mfma_f32_16x16x32_f16(pf, vf, o[qt], 0, 0, 0);
    }
  }

  // store: q = qt*16+4g+v, d = 16w+c
#pragma unroll
  for (int qt = 0; qt < 2; ++qt) {
#pragma unroll
    for (int v = 0; v < 4; ++v) {
      int q = qt * 16 + 4 * g + v;
      out[((long long)(b * 32 + q) << 10) + h * 64 + 16 * w + c] =
          o[qt][v] * invs[q];
    }
  }
}

// ---------------------------------------------------------------------------
extern "C" void kernel_launch(void* const* d_in, const int* in_sizes, int n_in,
                              void* d_out, int out_size, void* d_ws, size_t ws_size,
                              hipStream_t stream) {
  const float* Q_seq = (const float*)d_in[0];
  const float* K_seq = (const float*)d_in[1];
  const float* V_seq = (const float*)d_in[2];
  const float* title = (const float*)d_in[3];
  const float* body  = (const float*)d_in[4];
  const float* Wq = (const float*)d_in[5];
  const float* bq = (const float*)d_in[6];
  const float* Wk = (const float*)d_in[7];
  const float* bk = (const float*)d_in[8];
  const float* Wv = (const float*)d_in[9];
  const float* bv = (const float*)d_in[10];
  float* out = (float*)d_out;

  f16* ws = (f16*)d_ws;
  f16* Qb  = ws;
  f16* Kb  = Qb + 4194304;
  f16* Vb  = Kb + 16777216;
  f16* Wqb = Vb + 16777216;
  f16* Wkb = Wqb + 1048576;
  f16* Wvb = Wkb + 1048576;
  f16* Qh  = Wvb + 1048576;
  f16* Kh  = Qh + 4194304;
  f16* Vh  = Kh + 20971520;

  prep_kernel<<<39936, 256, 0, stream>>>(Q_seq, K_seq, V_seq, Wq, Wk, Wv,
                                         Qb, Kb, Vb, Wqb, Wkb, Wvb);
  gemm_kv<<<dim3(8, 128), 256, 0, stream>>>(Kb, Wkb, bk, Kh);
  gemm_kv<<<dim3(8, 128), 256, 0, stream>>>(Vb, Wvb, bv, Vh);
  gemm_q3<<<dim3(8, 32, 3), 256, 0, stream>>>(Qb, Wqb, Wkb, Wvb, bq, bk, bv,
                                              Qh, Kh, Vh);
  attn_kernel<<<2048, 256, 0, stream>>>(Qh, Kh, Vh, title, body, out);
}